// Round 8
// baseline (215.070 us; speedup 1.0000x reference)
//
#include <hip/hip_runtime.h>
#include <hip/hip_bf16.h>

// GAT layer, MI355X. B=32, N=512, Fin=256, F=64, H=8. fp32 in / fp32 out.
// R8 = R7 (64.2us: b-major XCD grid, fused, barrier-free stage 3) plus:
//  1. XOR-swizzled hT in LDS (16B blocks, blk^=f&7): R6 measured 5.24M->0.52M
//     bank conflicts on exactly this read pattern (~8.5us/CU of LDS stalls).
//  2. Transcendental-free inner loop: p = (Ei*Fj > 1) ? Ei*Fj : Gi*Hj, with
//     E=2^s_src, G=2^(0.2 s_src), F=2^s_dst, H=2^(0.2 s_dst) per node
//     (2048 exp2/block in stage 2 vs 262144 in the ks loop).
//  3. adj prefetch deepened to 2 ks-steps.

#define ALPHA  0.2f
#define ESCALE 1.4426950408889634f   // log2(e), folded into a at stage 0

typedef __bf16 bf16x8 __attribute__((ext_vector_type(8)));
typedef __bf16 bf16x4 __attribute__((ext_vector_type(4)));
typedef float  f32x4  __attribute__((ext_vector_type(4)));

#if __has_builtin(__builtin_amdgcn_exp2f)
#define EXP2(x) __builtin_amdgcn_exp2f(x)
#else
#define EXP2(x) exp2f(x)
#endif

#define WT_STRIDE 264   // 256+8

struct Smem {
    __bf16 hT[64 * 512];            // h^T [f][j], 16B-block XOR swizzle  65,536 B
    __bf16 WT[64][WT_STRIDE];       // W cols [n][k]                     33,792 B
    float  E[512], G[512], F[512], H[512];   //                           8,192 B
    float  asrc[64], adst[64];      //                                      512 B
};                                  // 108,032 B -> 1 block/CU

__device__ inline bf16x8 ld8(const float* p) {
    float4 a0 = *(const float4*)p;
    float4 a1 = *(const float4*)(p + 4);
    bf16x8 r;
    r[0]=(__bf16)a0.x; r[1]=(__bf16)a0.y; r[2]=(__bf16)a0.z; r[3]=(__bf16)a0.w;
    r[4]=(__bf16)a1.x; r[5]=(__bf16)a1.y; r[6]=(__bf16)a1.z; r[7]=(__bf16)a1.w;
    return r;
}

__global__ __launch_bounds__(512, 1) void k_gat(const float* __restrict__ x,
                                                const float* __restrict__ adj,
                                                const float* __restrict__ W,
                                                const float* __restrict__ a,
                                                float* __restrict__ out) {
    __shared__ Smem sm;
    const int b = blockIdx.x, h = blockIdx.y;    // b-major: h-blocks share XCD
    const int tid  = threadIdx.x;
    const int wave = tid >> 6, lane = tid & 63;
    const int quad = lane >> 4, col = lane & 15;

    // stage 0: a * log2e -> LDS; W head-slice fp32->bf16 -> LDS
    if (tid < 128) {
        float v = a[h * 128 + tid] * ESCALE;
        if (tid < 64) sm.asrc[tid] = v; else sm.adst[tid - 64] = v;
    }
    {
        int c = tid & 63, k0 = tid >> 6;             // coalesced in c
        #pragma unroll 4
        for (int t = 0; t < 32; ++t)
            sm.WT[c][k0 + t * 8] = (__bf16)W[(long)(k0 + t * 8) * 512 + h * 64 + c];
    }
    __syncthreads();

    // stage 1: h = x[b] @ W[:,h-block] -> swizzled hT  (MFMA 16x16x32)
    {
        const float* xb = x + (long)b * 512 * 256;
        f32x4 acc[4][4] = {};
        for (int ks = 0; ks < 8; ++ks) {             // K = 256
            int k0 = ks * 32 + quad * 8;
            bf16x8 av[4], bv[4];
            #pragma unroll
            for (int it = 0; it < 4; ++it)           // A[m=col][k=quad*8+u]
                av[it] = ld8(xb + (long)(wave * 64 + it * 16 + col) * 256 + k0);
            #pragma unroll
            for (int nt = 0; nt < 4; ++nt)           // B[k][n=col]
                bv[nt] = *(const bf16x8*)(&sm.WT[nt * 16 + col][k0]);
            #pragma unroll
            for (int it = 0; it < 4; ++it)
                #pragma unroll
                for (int nt = 0; nt < 4; ++nt)
                    acc[it][nt] = __builtin_amdgcn_mfma_f32_16x16x32_bf16(av[it], bv[nt], acc[it][nt], 0, 0, 0);
        }
        #pragma unroll
        for (int it = 0; it < 4; ++it)
            #pragma unroll
            for (int nt = 0; nt < 4; ++nt) {
                int f = nt * 16 + col;               // C/D: col=f, row=node
                int j = wave * 64 + it * 16 + quad * 4;
                int bb = j >> 3;                     // 16B-block XOR swizzle
                bf16x4 pk = { (__bf16)acc[it][nt][0], (__bf16)acc[it][nt][1],
                              (__bf16)acc[it][nt][2], (__bf16)acc[it][nt][3] };
                *(bf16x4*)(&sm.hT[f * 512 + ((bb ^ (f & 7)) << 3) + (j & 7)]) = pk;
            }
    }
    __syncthreads();

    // stage 2: per-node scores -> E,G,F,H (exp2 factor tables)
    {
        float as = 0.f, ad = 0.f;
        int bb = tid >> 3, off = tid & 7;
        #pragma unroll 8
        for (int f = 0; f < 64; ++f) {
            float v = (float)sm.hT[f * 512 + ((bb ^ (f & 7)) << 3) + off];
            as += v * sm.asrc[f];
            ad += v * sm.adst[f];
        }
        sm.E[tid] = EXP2(as);            // 2^(s_src*log2e) = e^{s_src}
        sm.G[tid] = EXP2(ALPHA * as);
        sm.F[tid] = EXP2(ad);
        sm.H[tid] = EXP2(ALPHA * ad);
    }
    __syncthreads();

    // stage 3: P-gen (no exp!) + P@h MFMA, 2-deep adj prefetch, no barriers
    {
        float EI[4], GI[4];
        const float* arow[4];
        #pragma unroll
        for (int it = 0; it < 4; ++it) {
            int i = wave * 64 + it * 16 + col;       // A-row m = lane&15
            EI[it]   = sm.E[i];
            GI[it]   = sm.G[i];
            arow[it] = adj + ((long)b * 512 + i) * 512;
        }
        bf16x8 ones;
        #pragma unroll
        for (int u = 0; u < 8; ++u) ones[u] = (__bf16)1.0f;

        f32x4 acc[4][4] = {};
        f32x4 accs[4]   = {};                        // row sums via P@ones
        float4 pa[2][4][2];                          // 2-deep prefetch
        #pragma unroll
        for (int d = 0; d < 2; ++d)
            #pragma unroll
            for (int it = 0; it < 4; ++it) {
                pa[d][it][0] = *(const float4*)(arow[it] + d * 32 + quad * 8);
                pa[d][it][1] = *(const float4*)(arow[it] + d * 32 + quad * 8 + 4);
            }
        for (int ks = 0; ks < 16; ++ks) {            // K = 512 neighbors
            int j0 = ks * 32 + quad * 8;
            int cur = ks & 1;
            float am[4][8];
            #pragma unroll
            for (int it = 0; it < 4; ++it) {         // consume slot `cur`
                am[it][0]=pa[cur][it][0].x; am[it][1]=pa[cur][it][0].y;
                am[it][2]=pa[cur][it][0].z; am[it][3]=pa[cur][it][0].w;
                am[it][4]=pa[cur][it][1].x; am[it][5]=pa[cur][it][1].y;
                am[it][6]=pa[cur][it][1].z; am[it][7]=pa[cur][it][1].w;
            }
            if (ks < 14) {                           // refill with ks+2
                #pragma unroll
                for (int it = 0; it < 4; ++it) {
                    pa[cur][it][0] = *(const float4*)(arow[it] + j0 + 64);
                    pa[cur][it][1] = *(const float4*)(arow[it] + j0 + 68);
                }
            }
            f32x4 F0 = *(const f32x4*)&sm.F[j0];
            f32x4 F1 = *(const f32x4*)&sm.F[j0 + 4];
            f32x4 H0 = *(const f32x4*)&sm.H[j0];
            f32x4 H1 = *(const f32x4*)&sm.H[j0 + 4];
            float Fv[8] = {F0[0],F0[1],F0[2],F0[3],F1[0],F1[1],F1[2],F1[3]};
            float Hv[8] = {H0[0],H0[1],H0[2],H0[3],H1[0],H1[1],H1[2],H1[3]};
            bf16x8 P[4];
            #pragma unroll
            for (int it = 0; it < 4; ++it)
                #pragma unroll
                for (int u = 0; u < 8; ++u) {
                    float ef = EI[it] * Fv[u];       // 2^(si+sj)
                    float gh = GI[it] * Hv[u];       // 2^(0.2(si+sj))
                    float p  = (ef > 1.0f ? ef : gh) * am[it][u];  // lrelu+mask
                    P[it][u] = (__bf16)p;
                }
            bf16x8 bv[4];
            #pragma unroll
            for (int nt = 0; nt < 4; ++nt) {         // swizzled read-back
                int f = nt * 16 + col;
                bv[nt] = *(const bf16x8*)(&sm.hT[f * 512 + (((ks * 4 + quad) ^ (f & 7)) << 3)]);
            }
            #pragma unroll
            for (int it = 0; it < 4; ++it) {
                #pragma unroll
                for (int nt = 0; nt < 4; ++nt)
                    acc[it][nt] = __builtin_amdgcn_mfma_f32_16x16x32_bf16(P[it], bv[nt], acc[it][nt], 0, 0, 0);
                accs[it] = __builtin_amdgcn_mfma_f32_16x16x32_bf16(P[it], ones, accs[it], 0, 0, 0);
            }
        }
        // epilogue: accs rows (quad*4+r) align with acc rows; no barrier
        #pragma unroll
        for (int it = 0; it < 4; ++it)
            #pragma unroll
            for (int r = 0; r < 4; ++r) {
                float s = accs[it][r];
                float inv = (s > 0.f) ? 1.0f / s : 0.f;
                int i = wave * 64 + it * 16 + quad * 4 + r;
                float* orow = out + ((long)b * 512 + i) * 512 + h * 64;
                #pragma unroll
                for (int nt = 0; nt < 4; ++nt)
                    orow[nt * 16 + col] = acc[it][nt][r] * inv;
            }
    }
}

// ---------------- launch ---------------------------------------------------
extern "C" void kernel_launch(void* const* d_in, const int* in_sizes, int n_in,
                              void* d_out, int out_size, void* d_ws, size_t ws_size,
                              hipStream_t stream) {
    const float* x   = (const float*)d_in[0];   // (32,512,256)
    const float* adj = (const float*)d_in[1];   // (32,512,512), {0,1}
    const float* W   = (const float*)d_in[2];   // (256,512)
    const float* a   = (const float*)d_in[3];   // (8,128)
    float* out = (float*)d_out;                 // (32,512,512)
    (void)d_ws; (void)ws_size;

    k_gat<<<dim3(32, 8), 512, 0, stream>>>(x, adj, W, a, out);
}

// Round 9
// 144.015 us; speedup vs baseline: 1.4934x; 1.4934x over previous
//
#include <hip/hip_runtime.h>
#include <hip/hip_bf16.h>

// GAT layer, MI355X. B=32, N=512, Fin=256, F=64, H=8. fp32 in / fp32 out.
// R9 = R7 (64us; b-major XCD grid, fused, barrier-free stage 3) plus:
//  1. adj pre-packed to a bitmask by k_pack: 33.5 MB fp32 -> 1 MB, layout
//     mask[b][ks][i] so stage-3 loads are 64B broadcast dwords, fully
//     L2-resident (128 KB/XCD vs 6 MB before). R7's stall was adj latency.
//  2. statically-indexed depth-1 prefetch (R8's pa[ks&1] dynamic indexing
//     spilled to scratch: WRITE_SIZE 32->270 MB, the whole regression).
//  3. keep R8's transcendental-free P-gen (E*F>1 ? E*F : G*H), verified.
//  4. plain 520-stride hT (R8 proved swizzle irrelevant to the 5.24M
//     conflicts; they live in the WT/stage-0 path, not hT b128 reads).

#define ALPHA  0.2f
#define ESCALE 1.4426950408889634f   // log2(e)

typedef __bf16 bf16x8 __attribute__((ext_vector_type(8)));
typedef __bf16 bf16x4 __attribute__((ext_vector_type(4)));
typedef float  f32x4  __attribute__((ext_vector_type(4)));

#if __has_builtin(__builtin_amdgcn_exp2f)
#define EXP2(x) __builtin_amdgcn_exp2f(x)
#else
#define EXP2(x) exp2f(x)
#endif

#define HT_STRIDE 520   // 512+8
#define WT_STRIDE 264   // 256+8

struct Smem {
    __bf16 hT[64][HT_STRIDE];              // h^T [f][j]        66,560 B
    __bf16 WT[64][WT_STRIDE];              // W cols [n][k]     33,792 B
    float  E[512], G[512], F[512], H[512]; //                    8,192 B
    float  asrc[64], adst[64];             //                       512 B
};                                         // 109,056 B -> 1 block/CU

__device__ inline bf16x8 ld8(const float* p) {
    float4 a0 = *(const float4*)p;
    float4 a1 = *(const float4*)(p + 4);
    bf16x8 r;
    r[0]=(__bf16)a0.x; r[1]=(__bf16)a0.y; r[2]=(__bf16)a0.z; r[3]=(__bf16)a0.w;
    r[4]=(__bf16)a1.x; r[5]=(__bf16)a1.y; r[6]=(__bf16)a1.z; r[7]=(__bf16)a1.w;
    return r;
}

// ---- k_pack: adj {0,1} fp32 -> bitmask. mask[(b*16+ks)*512 + i], bit j&31 --
__global__ __launch_bounds__(512) void k_pack(const float* __restrict__ adj,
                                              unsigned int* __restrict__ mask) {
    const int i = blockIdx.x, b = blockIdx.y;
    const int tid = threadIdx.x, wave = tid >> 6, lane = tid & 63;
    float v = adj[((long)b * 512 + i) * 512 + tid];          // coalesced
    unsigned long long m = __ballot(v > 0.f);                // 64 j-bits
    if (lane == 0) {
        mask[(b * 16 + 2 * wave) * 512 + i]     = (unsigned int)m;
        mask[(b * 16 + 2 * wave + 1) * 512 + i] = (unsigned int)(m >> 32);
    }
}

// ---- fused GAT kernel; USEM: bitmask path, else direct fp32 adj ----------
template <bool USEM>
__global__ __launch_bounds__(512, 1) void k_gat(const float* __restrict__ x,
                                                const float* __restrict__ adj,
                                                const unsigned int* __restrict__ mask,
                                                const float* __restrict__ W,
                                                const float* __restrict__ a,
                                                float* __restrict__ out) {
    __shared__ Smem sm;
    const int b = blockIdx.x, h = blockIdx.y;    // b-major: h-blocks share XCD
    const int tid  = threadIdx.x;
    const int wave = tid >> 6, lane = tid & 63;
    const int quad = lane >> 4, col = lane & 15;

    // stage 0: a * log2e -> LDS; W head-slice fp32->bf16 -> LDS
    if (tid < 128) {
        float v = a[h * 128 + tid] * ESCALE;
        if (tid < 64) sm.asrc[tid] = v; else sm.adst[tid - 64] = v;
    }
    {
        int c = tid & 63, k0 = tid >> 6;             // coalesced in c
        #pragma unroll 4
        for (int t = 0; t < 32; ++t)
            sm.WT[c][k0 + t * 8] = (__bf16)W[(long)(k0 + t * 8) * 512 + h * 64 + c];
    }
    __syncthreads();

    // stage 1: h = x[b] @ W[:,h-block] -> hT[f][j]  (MFMA 16x16x32)
    {
        const float* xb = x + (long)b * 512 * 256;
        f32x4 acc[4][4] = {};
        for (int ks = 0; ks < 8; ++ks) {             // K = 256
            int k0 = ks * 32 + quad * 8;
            bf16x8 av[4], bv[4];
            #pragma unroll
            for (int it = 0; it < 4; ++it)           // A[m=col][k=quad*8+u]
                av[it] = ld8(xb + (long)(wave * 64 + it * 16 + col) * 256 + k0);
            #pragma unroll
            for (int nt = 0; nt < 4; ++nt)           // B[k][n=col]
                bv[nt] = *(const bf16x8*)(&sm.WT[nt * 16 + col][k0]);
            #pragma unroll
            for (int it = 0; it < 4; ++it)
                #pragma unroll
                for (int nt = 0; nt < 4; ++nt)
                    acc[it][nt] = __builtin_amdgcn_mfma_f32_16x16x32_bf16(av[it], bv[nt], acc[it][nt], 0, 0, 0);
        }
        #pragma unroll
        for (int it = 0; it < 4; ++it)
            #pragma unroll
            for (int nt = 0; nt < 4; ++nt) {
                int f = nt * 16 + col;               // C/D: col=f, row=node
                int j = wave * 64 + it * 16 + quad * 4;
                bf16x4 pk = { (__bf16)acc[it][nt][0], (__bf16)acc[it][nt][1],
                              (__bf16)acc[it][nt][2], (__bf16)acc[it][nt][3] };
                *(bf16x4*)(&sm.hT[f][j]) = pk;
            }
    }
    __syncthreads();

    // stage 2: per-node score factor tables E,G,F,H (only 2048 exp2/block)
    {
        float as = 0.f, ad = 0.f;
        #pragma unroll 8
        for (int f = 0; f < 64; ++f) {
            float v = (float)sm.hT[f][tid];
            as += v * sm.asrc[f];
            ad += v * sm.adst[f];
        }
        sm.E[tid] = EXP2(as);            // e^{s_src}
        sm.G[tid] = EXP2(ALPHA * as);
        sm.F[tid] = EXP2(ad);
        sm.H[tid] = EXP2(ALPHA * ad);
    }
    __syncthreads();

    // stage 3: P-gen (no exp) + P@h MFMA; static depth-1 prefetch
    {
        const int qs = quad * 8;
        float EI[4], GI[4];
        int iw[4];
        const float* arow[4];
        #pragma unroll
        for (int it = 0; it < 4; ++it) {
            int i = wave * 64 + it * 16 + col;       // A-row m = lane&15
            iw[it] = i;
            EI[it] = sm.E[i];
            GI[it] = sm.G[i];
            if (!USEM) arow[it] = adj + ((long)b * 512 + i) * 512;
        }
        const unsigned int* mbase = mask + (long)b * 16 * 512;
        bf16x8 ones;
        #pragma unroll
        for (int u = 0; u < 8; ++u) ones[u] = (__bf16)1.0f;

        f32x4 acc[4][4] = {};
        f32x4 accs[4]   = {};                        // row sums via P@ones
        unsigned int pm[4];
        float4 pa0[4], pa1[4];
        #pragma unroll
        for (int it = 0; it < 4; ++it) {             // prefetch ks=0 (static)
            if (USEM) pm[it] = mbase[iw[it]];
            else {
                pa0[it] = *(const float4*)(arow[it] + qs);
                pa1[it] = *(const float4*)(arow[it] + qs + 4);
            }
        }
        for (int ks = 0; ks < 16; ++ks) {            // K = 512 neighbors
            int j0 = ks * 32 + qs;
            unsigned int cm[4];
            float am[4][8];
            #pragma unroll
            for (int it = 0; it < 4; ++it) {         // consume prefetch
                if (USEM) cm[it] = pm[it];
                else {
                    am[it][0]=pa0[it].x; am[it][1]=pa0[it].y;
                    am[it][2]=pa0[it].z; am[it][3]=pa0[it].w;
                    am[it][4]=pa1[it].x; am[it][5]=pa1[it].y;
                    am[it][6]=pa1[it].z; am[it][7]=pa1[it].w;
                }
            }
            if (ks < 15) {                           // refill (static regs)
                #pragma unroll
                for (int it = 0; it < 4; ++it) {
                    if (USEM) pm[it] = mbase[(ks + 1) * 512 + iw[it]];
                    else {
                        pa0[it] = *(const float4*)(arow[it] + j0 + 32);
                        pa1[it] = *(const float4*)(arow[it] + j0 + 36);
                    }
                }
            }
            f32x4 F0 = *(const f32x4*)&sm.F[j0];
            f32x4 F1 = *(const f32x4*)&sm.F[j0 + 4];
            f32x4 H0 = *(const f32x4*)&sm.H[j0];
            f32x4 H1 = *(const f32x4*)&sm.H[j0 + 4];
            float Fv[8] = {F0[0],F0[1],F0[2],F0[3],F1[0],F1[1],F1[2],F1[3]};
            float Hv[8] = {H0[0],H0[1],H0[2],H0[3],H1[0],H1[1],H1[2],H1[3]};
            bf16x8 P[4];
            #pragma unroll
            for (int it = 0; it < 4; ++it)
                #pragma unroll
                for (int u = 0; u < 8; ++u) {
                    float ef = EI[it] * Fv[u];       // e^{si+sj}
                    float gh = GI[it] * Hv[u];       // e^{0.2(si+sj)}
                    float sel = ef > 1.0f ? ef : gh; // leaky-relu in exp-space
                    float p;
                    if (USEM) p = ((cm[it] >> (qs + u)) & 1u) ? sel : 0.0f;
                    else      p = sel * am[it][u];
                    P[it][u] = (__bf16)p;
                }
            bf16x8 bv[4];
            #pragma unroll
            for (int nt = 0; nt < 4; ++nt)
                bv[nt] = *(const bf16x8*)(&sm.hT[nt * 16 + col][j0]);
            #pragma unroll
            for (int it = 0; it < 4; ++it) {
                #pragma unroll
                for (int nt = 0; nt < 4; ++nt)
                    acc[it][nt] = __builtin_amdgcn_mfma_f32_16x16x32_bf16(P[it], bv[nt], acc[it][nt], 0, 0, 0);
                accs[it] = __builtin_amdgcn_mfma_f32_16x16x32_bf16(P[it], ones, accs[it], 0, 0, 0);
            }
        }
        // epilogue: accs rows (quad*4+r) align with acc rows; no barrier
        #pragma unroll
        for (int it = 0; it < 4; ++it)
            #pragma unroll
            for (int r = 0; r < 4; ++r) {
                float s = accs[it][r];
                float inv = (s > 0.f) ? 1.0f / s : 0.f;
                int i = wave * 64 + it * 16 + quad * 4 + r;
                float* orow = out + ((long)b * 512 + i) * 512 + h * 64;
                #pragma unroll
                for (int nt = 0; nt < 4; ++nt)
                    orow[nt * 16 + col] = acc[it][nt][r] * inv;
            }
    }
}

// ---------------- launch ---------------------------------------------------
extern "C" void kernel_launch(void* const* d_in, const int* in_sizes, int n_in,
                              void* d_out, int out_size, void* d_ws, size_t ws_size,
                              hipStream_t stream) {
    const float* x   = (const float*)d_in[0];   // (32,512,256)
    const float* adj = (const float*)d_in[1];   // (32,512,512), {0,1}
    const float* W   = (const float*)d_in[2];   // (256,512)
    const float* a   = (const float*)d_in[3];   // (8,128)
    float* out = (float*)d_out;                 // (32,512,512)

    const size_t MASK_BYTES = 32u * 16u * 512u * 4u;   // 1 MB
    if (ws_size >= MASK_BYTES) {
        unsigned int* mask = (unsigned int*)d_ws;
        k_pack<<<dim3(512, 32), 512, 0, stream>>>(adj, mask);
        k_gat<true><<<dim3(32, 8), 512, 0, stream>>>(x, adj, mask, W, a, out);
    } else {
        k_gat<false><<<dim3(32, 8), 512, 0, stream>>>(x, adj, nullptr, W, a, out);
    }
}